// Round 12
// baseline (3532.397 us; speedup 1.0000x reference)
//
#include <hip/hip_runtime.h>

#define NB 32
#define NT 1024
#define NH 512
#define NE 256
#define NV0 2048
#define NV1 512
#define G3H 1536
#define NCHUNK 16       // hh chunks (32 hh x 3 gates each)
#define FLAGTGT 32      // 16 chunk-blocks x 2 waves

typedef __attribute__((ext_vector_type(8))) short bf16x8;
typedef __attribute__((ext_vector_type(4))) float f32x4;
typedef unsigned short u16;
typedef unsigned int u32;
typedef unsigned long long u64;

__device__ __forceinline__ u16 bf16_hi(float x) {
  unsigned u = __float_as_uint(x);
  unsigned r = (u + 0x7FFF + ((u >> 16) & 1)) >> 16;
  return (u16)r;
}
__device__ __forceinline__ float bf16_f(u16 h) {
  return __uint_as_float(((unsigned)h) << 16);
}
__device__ __forceinline__ u32 pack_hl(float v) {
  u16 hi = bf16_hi(v);
  u16 lo = bf16_hi(v - bf16_f(hi));
  return (u32)hi | ((u32)lo << 16);
}
__device__ __forceinline__ float unpack_hl(u32 w) {
  return bf16_f((u16)w) + bf16_f((u16)(w >> 16));
}

// ---------------- prep ----------------

__global__ void k_transpose(const float* __restrict__ in, float* __restrict__ out) {
  __shared__ float tile[32][33];
  int bx = blockIdx.x, by = blockIdx.y;
  int x = threadIdx.x, y = threadIdx.y;
  #pragma unroll
  for (int j = 0; j < 4; ++j)
    tile[y + j * 8][x] = in[(by * 32 + y + j * 8) * 512 + bx * 32 + x];
  __syncthreads();
  #pragma unroll
  for (int j = 0; j < 4; ++j)
    out[(bx * 32 + y + j * 8) * 1536 + by * 32 + x] = tile[x][y + j * 8];
}

__global__ __launch_bounds__(256) void k_proj(const float* __restrict__ emb0,
                                              const float* __restrict__ emb1,
                                              const float* __restrict__ Wt_ih,
                                              float* __restrict__ proj0,
                                              float* __restrict__ proj1) {
  __shared__ float a[8][NE];
  int g0 = blockIdx.x * 8;
  int tid = threadIdx.x;
  for (int i = tid; i < 8 * NE; i += 256) {
    int v = g0 + (i >> 8);
    int k = i & 255;
    a[i >> 8][k] = (v < NV0) ? emb0[v * NE + k] : emb1[(v - NV0) * NE + k];
  }
  __syncthreads();
  bool is0 = (g0 < NV0);
  int koff = is0 ? 0 : NE;
  float acc[8][6];
  #pragma unroll
  for (int v = 0; v < 8; ++v)
    #pragma unroll
    for (int j = 0; j < 6; ++j) acc[v][j] = 0.f;
  for (int k = 0; k < NE; ++k) {
    const float* wrow = Wt_ih + (size_t)(k + koff) * G3H;
    float w[6];
    #pragma unroll
    for (int j = 0; j < 6; ++j) w[j] = wrow[tid + j * 256];
    #pragma unroll
    for (int v = 0; v < 8; ++v) {
      float av = a[v][k];
      #pragma unroll
      for (int j = 0; j < 6; ++j) acc[v][j] += av * w[j];
    }
  }
  float* outp = is0 ? (proj0 + (size_t)g0 * G3H) : (proj1 + (size_t)(g0 - NV0) * G3H);
  for (int v = 0; v < 8; ++v)
    for (int j = 0; j < 6; ++j)
      outp[(size_t)v * G3H + tid + j * 256] = acc[v][j];
}

// W_hh split: tile tt = (hh>>4)*3 + g  (32 hh16-blocks x 3 gates = 96 tiles of 16x512)
__global__ void k_wsplit(const float* __restrict__ W_hh, u16* __restrict__ Wfh,
                         u16* __restrict__ Wfl) {
  int idx = blockIdx.x * blockDim.x + threadIdx.x;
  if (idx >= G3H * NH) return;
  int row = idx >> 9, k = idx & 511;
  int g = row >> 9, hh = row & 511;
  int tt = (hh >> 4) * 3 + g;
  size_t phys = ((size_t)tt * 64 + (k >> 3)) * 128 + (hh & 15) * 8 + (k & 7);
  float v = W_hh[idx];
  u16 hi = bf16_hi(v);
  Wfh[phys] = hi;
  Wfl[phys] = bf16_hi(v - bf16_f(hi));
}

__global__ void k_wsplit_dec(const float* __restrict__ W, u16* __restrict__ Wh,
                             u16* __restrict__ Wl, int R) {
  int idx = blockIdx.x * blockDim.x + threadIdx.x;
  if (idx >= R * 512) return;
  int row = idx >> 9, k = idx & 511;
  size_t phys = ((size_t)(row >> 4) * 64 + (k >> 3)) * 128 + (row & 15) * 8 + (k & 7);
  float v = W[idx];
  u16 hi = bf16_hi(v);
  Wh[phys] = hi;
  Wl[phys] = bf16_hi(v - bf16_f(hi));
}

// Fused planning: one block per batch. Computes levels, builds level-ordered
// item list (groups of <=16) + node_list, inits state row 0 and gdone flags.
__global__ __launch_bounds__(256) void k_plan(const int* __restrict__ cond,
                                              const float* __restrict__ hidden,
                                              u32* __restrict__ bufp,
                                              int* __restrict__ gdone,
                                              int* __restrict__ items,
                                              int* __restrict__ nitems,
                                              int* __restrict__ node_list) {
  __shared__ int c_lds[NT];
  __shared__ int lvl[NT + 1];
  __shared__ int off[NT + 1];
  int b = blockIdx.x, tid = threadIdx.x;
  for (int h = tid; h < NH; h += 256) bufp[b * NH + h] = pack_hl(hidden[b * NH + h]);
  for (int f = tid; f < 1026; f += 256) gdone[b * 1026 + f] = (f == 0) ? FLAGTGT : 0;
  for (int i = tid; i < NT; i += 256) c_lds[i] = cond[b * NT + i];
  for (int i = tid; i <= NT; i += 256) off[i] = 0;
  __syncthreads();
  if (tid == 0) {
    lvl[0] = 0;
    for (int t = 0; t < NT; ++t) {
      int l = lvl[c_lds[t]] + 1;
      lvl[t + 1] = l;
      off[l - 1]++;                       // counts
    }
    int off0 = 0, io = 0;
    for (int p = 0; p <= NT; ++p) {
      int n = off[p];
      off[p] = off0;                      // counts -> offsets
      for (int g0 = 0; g0 < n; g0 += 16) {
        int nb = n - g0; if (nb > 16) nb = 16;
        items[b * 1024 + io++] = (p << 21) | ((b * 1024 + off0 + g0) << 6) | nb;
      }
      off0 += n;
    }
    nitems[b] = io;
    for (int t = 0; t < NT; ++t) {        // scatter (offsets become cursors)
      int p = lvl[t + 1] - 1;
      node_list[b * 1024 + off[p]++] = (b << 16) | t;
    }
  }
}

// ---------------- recurrence: per-batch level streams (r10 structure) ----------------
// Grid = 16 chunks x 32 batches = 512 blocks of 128 threads (2 waves), 2 blocks/CU.
// Block (c,b) walks batch b's levels in order; a node at level p has its single
// parent at EXACTLY level p-1 (same batch), so each hop needs ONE flag:
// gdone[b][p] counted to 32 by per-WAVE release publishes after per-wave
// vmcnt(0) drains (r9/r11-proven discipline). Consumer relaxed-polls one L3 addr.

__global__ __launch_bounds__(128, 8) void rnn_steps(
    const int* __restrict__ items, const int* __restrict__ nitems,
    const int* __restrict__ node_list, const int* __restrict__ cond,
    const int* __restrict__ tok0, const int* __restrict__ tok1,
    const u16* __restrict__ Wfh, const u16* __restrict__ Wfl,
    const float* __restrict__ proj0, const float* __restrict__ proj1,
    const float* __restrict__ b_ih, const float* __restrict__ b_hh,
    u32* __restrict__ bufp, int* gdone) {
  __shared__ unsigned char hds_h[16 * 1024];
  __shared__ unsigned char hds_l[16 * 1024];
  __shared__ int s_tb[16], s_par[16], s_k0[16], s_k1[16];
  int tid = threadIdx.x;
  int w = tid >> 6, lane = tid & 63, q = lane >> 4, m = lane & 15;
  int c = blockIdx.x & (NCHUNK - 1);
  int b = blockIdx.x >> 4;
  int nIt = nitems[b];
  const int* myItems = items + b * 1024;
  int* myGd = gdone + b * 1026;
  int prevp = -1;
  for (int j = 0; j < nIt; ++j) {
    __syncthreads();   // protect LDS from previous item
    int desc = myItems[j];
    int p = desc >> 21;
    int start = (desc >> 6) & 0x7FFF;
    int nb = desc & 63;
    if (tid < 16) {
      int bb = 0, t = -1, par = 0, q0 = 0, q1 = 0;
      if (tid < nb) {
        int pk = node_list[start + tid];
        bb = pk >> 16; t = pk & 0xFFFF;
        par = cond[bb * NT + t];
        q0 = tok0[bb * NT + t];
        q1 = tok1[bb * NT + t];
      }
      s_tb[tid] = (t + 1) * NB + bb;
      s_par[tid] = par * NB + bb;
      s_k0[tid] = q0; s_k1[tid] = q1;
    }
    __syncthreads();
    // ---- gi gather (independent of parents): seeds accumulators, pre-poll ----
    int hb = c * 2 + w;          // hh16-block owned by this wave
    int hh = hb * 16 + m;
    float bir = b_ih[hh] + b_hh[hh];
    float biz = b_ih[NH + hh] + b_hh[NH + hh];
    float bin = b_ih[2 * NH + hh];
    float bhn = b_hh[2 * NH + hh];
    f32x4 aR, aZ, aN;
    float gin[4];
    #pragma unroll
    for (int i = 0; i < 4; ++i) {
      int node = q * 4 + i;
      const float* p0 = proj0 + (size_t)s_k0[node] * G3H;
      const float* p1 = proj1 + (size_t)s_k1[node] * G3H;
      aR[i] = p0[hh] + p1[hh] + bir;
      aZ[i] = p0[NH + hh] + p1[NH + hh] + biz;
      gin[i] = p0[2 * NH + hh] + p1[2 * NH + hh] + bin;
      aN[i] = bhn;
    }
    // ---- dependency poll: ONE flag (parent level complete for this batch) ----
    if (p != prevp) {
      if (tid == 0) {
        while (__hip_atomic_load(&myGd[p], __ATOMIC_RELAXED, __HIP_MEMORY_SCOPE_AGENT)
               < FLAGTGT)
          __builtin_amdgcn_s_sleep(1);
      }
      prevp = p;
    }
    __syncthreads();
    asm volatile("" ::: "memory");
    // ---- stage nb parent states into split hi/lo LDS (swizzled) ----
    for (int idx = tid; idx < nb * 16; idx += 128) {
      int r = idx >> 4, seg = idx & 15;
      size_t src = (size_t)s_par[r] * NH + seg * 32;
      u64 dv[16];
      #pragma unroll
      for (int k2 = 0; k2 < 16; ++k2)
        dv[k2] = __hip_atomic_load((const u64*)&bufp[src + k2 * 2],
                                   __ATOMIC_RELAXED, __HIP_MEMORY_SCOPE_AGENT);
      int swz = (r & 7) << 4;
      #pragma unroll
      for (int k2 = 0; k2 < 16; ++k2) {
        u32 e0 = (u32)dv[k2], e1 = (u32)(dv[k2] >> 32);
        int wi = seg * 32 + k2 * 2;
        int a = r * 1024 + (((wi >> 3) * 16) ^ swz) + ((2 * wi) & 15);
        *(u32*)(hds_h + a) = (e0 & 0xFFFFu) | (e1 << 16);
        *(u32*)(hds_l + a) = (e0 >> 16) | (e1 & 0xFFFF0000u);
      }
    }
    __syncthreads();
    // ---- MFMA: wave owns hb = c*2+w, 3 gates, 16 nodes, K=512, 3-split ----
    {
      const u16* wh = Wfh + (size_t)hb * 3 * 8192;
      const u16* wl = Wfl + (size_t)hb * 3 * 8192;
      #pragma unroll 4
      for (int s = 0; s < 16; ++s) {
        int ab = m * 1024 + (((s * 64) + (q * 16)) ^ ((m & 7) << 4));
        bf16x8 ah = *(const bf16x8*)(hds_h + ab);
        bf16x8 al = *(const bf16x8*)(hds_l + ab);
        int koff = (s * 4 + q) * 128 + m * 8;
        bf16x8 bh0 = *(const bf16x8*)(wh + koff);
        bf16x8 bl0 = *(const bf16x8*)(wl + koff);
        bf16x8 bh1 = *(const bf16x8*)(wh + 8192 + koff);
        bf16x8 bl1 = *(const bf16x8*)(wl + 8192 + koff);
        bf16x8 bh2 = *(const bf16x8*)(wh + 16384 + koff);
        bf16x8 bl2 = *(const bf16x8*)(wl + 16384 + koff);
        aR = __builtin_amdgcn_mfma_f32_16x16x32_bf16(ah, bh0, aR, 0, 0, 0);
        aR = __builtin_amdgcn_mfma_f32_16x16x32_bf16(ah, bl0, aR, 0, 0, 0);
        aR = __builtin_amdgcn_mfma_f32_16x16x32_bf16(al, bh0, aR, 0, 0, 0);
        aZ = __builtin_amdgcn_mfma_f32_16x16x32_bf16(ah, bh1, aZ, 0, 0, 0);
        aZ = __builtin_amdgcn_mfma_f32_16x16x32_bf16(ah, bl1, aZ, 0, 0, 0);
        aZ = __builtin_amdgcn_mfma_f32_16x16x32_bf16(al, bh1, aZ, 0, 0, 0);
        aN = __builtin_amdgcn_mfma_f32_16x16x32_bf16(ah, bh2, aN, 0, 0, 0);
        aN = __builtin_amdgcn_mfma_f32_16x16x32_bf16(ah, bl2, aN, 0, 0, 0);
        aN = __builtin_amdgcn_mfma_f32_16x16x32_bf16(al, bh2, aN, 0, 0, 0);
      }
      // ---- in-register GRU epilogue; packed u32 agent-atomic state stores ----
      #pragma unroll
      for (int i = 0; i < 4; ++i) {
        int node = q * 4 + i;
        if (node < nb) {
          float rg = 1.f / (1.f + __expf(-aR[i]));
          float zg = 1.f / (1.f + __expf(-aZ[i]));
          float nn = 1.f - 2.f / (1.f + __expf(2.f * (gin[i] + rg * aN[i])));
          int hofs = node * 1024 + ((hh * 2) ^ ((node & 7) << 4));
          float hp = bf16_f(*(const u16*)(hds_h + hofs)) + bf16_f(*(const u16*)(hds_l + hofs));
          float hn = (1.f - zg) * nn + zg * hp;
          __hip_atomic_store(&bufp[(size_t)s_tb[node] * NH + hh], pack_hl(hn),
                             __ATOMIC_RELAXED, __HIP_MEMORY_SCOPE_AGENT);
        }
      }
    }
    // ---- per-WAVE drain + release publish (once per level per wave) ----
    bool lastOfLevel = (j == nIt - 1) || ((myItems[j + 1] >> 21) != p);
    asm volatile("s_waitcnt vmcnt(0)" ::: "memory");
    if (lastOfLevel && lane == 0)
      __hip_atomic_fetch_add(&myGd[p + 1], 1, __ATOMIC_RELEASE,
                             __HIP_MEMORY_SCOPE_AGENT);
  }
}

// ---------------- decode GEMM: MFMA bf16 3-split, 64x128 tiles ----------------

__global__ __launch_bounds__(256) void k_dec(const u32* __restrict__ bufp,
                                             const u16* __restrict__ Wh,
                                             const u16* __restrict__ Wl,
                                             const float* __restrict__ bias,
                                             float* __restrict__ out, int N) {
  __shared__ u16 Ah[64 * 128];
  __shared__ u16 Al[64 * 128];
  int tid = threadIdx.x;
  int w = tid >> 6, lane = tid & 63, q = lane >> 4, m = lane & 15;
  int n0 = blockIdx.x * 128, m0 = blockIdx.y * 64;
  f32x4 acc[8];
  #pragma unroll
  for (int n = 0; n < 8; ++n) acc[n] = (f32x4){0.f, 0.f, 0.f, 0.f};
  for (int c = 0; c < 4; ++c) {
    __syncthreads();
    #pragma unroll
    for (int r = 0; r < 8; ++r) {
      int idx = r * 256 + tid;           // 2048 16B-loads = 64 rows x 32 segs
      int row = idx >> 5, seg = idx & 31;
      int gm = m0 + row;
      size_t bufrow = (size_t)((gm & (NT - 1)) + 1) * NB + (gm >> 10);
      uint4 vv = *(const uint4*)(bufp + bufrow * NH + c * 128 + seg * 4);
      int a = row * 256 + (((seg >> 1) * 16) ^ ((row & 7) << 4)) + (seg & 1) * 8;
      uint2 hp, lp;
      hp.x = (vv.x & 0xFFFFu) | (vv.y << 16);
      hp.y = (vv.z & 0xFFFFu) | (vv.w << 16);
      lp.x = (vv.x >> 16) | (vv.y & 0xFFFF0000u);
      lp.y = (vv.z >> 16) | (vv.w & 0xFFFF0000u);
      *(uint2*)((unsigned char*)Ah + a) = hp;
      *(uint2*)((unsigned char*)Al + a) = lp;
    }
    __syncthreads();
    #pragma unroll
    for (int s = 0; s < 4; ++s) {
      int arow = w * 16 + m;
      int aoff = arow * 256 + (((s * 64) + (q * 16)) ^ ((arow & 7) << 4));
      bf16x8 ah = *(const bf16x8*)((unsigned char*)Ah + aoff);
      bf16x8 al = *(const bf16x8*)((unsigned char*)Al + aoff);
      #pragma unroll
      for (int n = 0; n < 8; ++n) {
        size_t bo = ((size_t)(n0 / 16 + n) * 64 + (c * 16 + s * 4 + q)) * 128 + m * 8;
        bf16x8 bh = *(const bf16x8*)(Wh + bo);
        bf16x8 bl = *(const bf16x8*)(Wl + bo);
        acc[n] = __builtin_amdgcn_mfma_f32_16x16x32_bf16(ah, bh, acc[n], 0, 0, 0);
        acc[n] = __builtin_amdgcn_mfma_f32_16x16x32_bf16(ah, bl, acc[n], 0, 0, 0);
        acc[n] = __builtin_amdgcn_mfma_f32_16x16x32_bf16(al, bh, acc[n], 0, 0, 0);
      }
    }
  }
  #pragma unroll
  for (int n = 0; n < 8; ++n) {
    int col = n0 + n * 16 + m;
    float bv = bias[col];
    #pragma unroll
    for (int i = 0; i < 4; ++i) {
      int mrow = m0 + w * 16 + q * 4 + i;
      out[(size_t)mrow * N + col] = acc[n][i] + bv;
    }
  }
}

__global__ void k_tail(const u32* __restrict__ bufp, float* __restrict__ out) {
  int i = blockIdx.x * blockDim.x + threadIdx.x;
  if (i < NB * NH) out[i] = unpack_hl(bufp[(size_t)NT * NB * NH + i]);
}

// ---------------- launch ----------------

extern "C" void kernel_launch(void* const* d_in, const int* in_sizes, int n_in,
                              void* d_out, int out_size, void* d_ws, size_t ws_size,
                              hipStream_t stream) {
  const int*   tokens0    = (const int*)d_in[0];
  const int*   tokens1    = (const int*)d_in[1];
  const int*   conditions = (const int*)d_in[2];
  const float* hidden     = (const float*)d_in[3];
  const float* emb0       = (const float*)d_in[4];
  const float* emb1       = (const float*)d_in[5];
  const float* W_ih       = (const float*)d_in[6];
  const float* W_hh       = (const float*)d_in[7];
  const float* b_ih       = (const float*)d_in[8];
  const float* b_hh       = (const float*)d_in[9];
  const float* dec0_W     = (const float*)d_in[10];
  const float* dec0_b     = (const float*)d_in[11];
  const float* dec1_W     = (const float*)d_in[12];
  const float* dec1_b     = (const float*)d_in[13];

  char* wsb = (char*)d_ws;
  float* proj0 = (float*)wsb;                      // 12,582,912 B
  float* proj1 = (float*)(wsb + 12582912);         //  3,145,728 B
  float* Wt_ih = (float*)(wsb + 15728640);         //  3,145,728 B (reused below)
  // gdone/items/nitems overlay Wt_ih's region: used only AFTER k_proj
  int*   gdone   = (int*)(wsb + 15728640);         // 32*1026 ints = 131,328 B
  int*   items   = (int*)(wsb + 15859968);         // 32*1024 ints = 131,072 B
  int*   nitems  = (int*)(wsb + 15991040);         // 32 ints
  u32*   bufp  = (u32*)(wsb + 18874368);           // 1025*32*512 u32 = 67,174,400 B
  u16*   Wfh   = (u16*)(wsb + 86048768);           //  1,572,864 B
  u16*   Wfl   = (u16*)(wsb + 87621632);           //  1,572,864 B
  u16*   d0Wh  = (u16*)(wsb + 89194496);           //  2,097,152 B
  u16*   d0Wl  = (u16*)(wsb + 91291648);           //  2,097,152 B
  u16*   d1Wh  = (u16*)(wsb + 93388800);           //    524,288 B
  u16*   d1Wl  = (u16*)(wsb + 93913088);           //    524,288 B
  int*   node_list = (int*)(wsb + 94437376);       // 32768 ints

  float* out0 = (float*)d_out;
  float* out1 = out0 + (size_t)NB * NT * NV0;
  float* outT = out1 + (size_t)NB * NT * NV1;

  // Wt_ih produced+consumed first; then its region is reused for dataflow state.
  k_transpose<<<dim3(16, 48), dim3(32, 8), 0, stream>>>(W_ih, Wt_ih);
  k_proj<<<320, 256, 0, stream>>>(emb0, emb1, Wt_ih, proj0, proj1);
  k_wsplit<<<3072, 256, 0, stream>>>(W_hh, Wfh, Wfl);
  k_wsplit_dec<<<4096, 256, 0, stream>>>(dec0_W, d0Wh, d0Wl, NV0);
  k_wsplit_dec<<<1024, 256, 0, stream>>>(dec1_W, d1Wh, d1Wl, NV1);
  k_plan<<<NB, 256, 0, stream>>>(conditions, hidden, bufp, gdone, items, nitems,
                                 node_list);

  rnn_steps<<<NCHUNK * NB, 128, 0, stream>>>(items, nitems, node_list, conditions,
                                             tokens0, tokens1, Wfh, Wfl, proj0, proj1,
                                             b_ih, b_hh, bufp, gdone);

  k_dec<<<dim3(NV0 / 128, (NB * NT) / 64), 256, 0, stream>>>(bufp, d0Wh, d0Wl, dec0_b, out0, NV0);
  k_dec<<<dim3(NV1 / 128, (NB * NT) / 64), 256, 0, stream>>>(bufp, d1Wh, d1Wl, dec1_b, out1, NV1);
  k_tail<<<64, 256, 0, stream>>>(bufp, outT);
}

// Round 13
// 2871.259 us; speedup vs baseline: 1.2303x; 1.2303x over previous
//
#include <hip/hip_runtime.h>

#define NB 32
#define NT 1024
#define NH 512
#define NE 256
#define NV0 2048
#define NV1 512
#define G3H 1536
#define NCHUNK 16       // hh chunks (32 hh x 3 gates each)
#define FLAGTGT 16      // 16 chunk-blocks, one RMW each (r10-proven minimum)

typedef __attribute__((ext_vector_type(8))) short bf16x8;
typedef __attribute__((ext_vector_type(4))) float f32x4;
typedef unsigned short u16;
typedef unsigned int u32;
typedef unsigned long long u64;

__device__ __forceinline__ u16 bf16_hi(float x) {
  unsigned u = __float_as_uint(x);
  unsigned r = (u + 0x7FFF + ((u >> 16) & 1)) >> 16;
  return (u16)r;
}
__device__ __forceinline__ float bf16_f(u16 h) {
  return __uint_as_float(((unsigned)h) << 16);
}
__device__ __forceinline__ u32 pack_hl(float v) {
  u16 hi = bf16_hi(v);
  u16 lo = bf16_hi(v - bf16_f(hi));
  return (u32)hi | ((u32)lo << 16);
}
__device__ __forceinline__ float unpack_hl(u32 w) {
  return bf16_f((u16)w) + bf16_f((u16)(w >> 16));
}

// ---------------- prep ----------------

__global__ void k_transpose(const float* __restrict__ in, float* __restrict__ out) {
  __shared__ float tile[32][33];
  int bx = blockIdx.x, by = blockIdx.y;
  int x = threadIdx.x, y = threadIdx.y;
  #pragma unroll
  for (int j = 0; j < 4; ++j)
    tile[y + j * 8][x] = in[(by * 32 + y + j * 8) * 512 + bx * 32 + x];
  __syncthreads();
  #pragma unroll
  for (int j = 0; j < 4; ++j)
    out[(bx * 32 + y + j * 8) * 1536 + by * 32 + x] = tile[x][y + j * 8];
}

__global__ __launch_bounds__(256) void k_proj(const float* __restrict__ emb0,
                                              const float* __restrict__ emb1,
                                              const float* __restrict__ Wt_ih,
                                              float* __restrict__ proj0,
                                              float* __restrict__ proj1) {
  __shared__ float a[8][NE];
  int g0 = blockIdx.x * 8;
  int tid = threadIdx.x;
  for (int i = tid; i < 8 * NE; i += 256) {
    int v = g0 + (i >> 8);
    int k = i & 255;
    a[i >> 8][k] = (v < NV0) ? emb0[v * NE + k] : emb1[(v - NV0) * NE + k];
  }
  __syncthreads();
  bool is0 = (g0 < NV0);
  int koff = is0 ? 0 : NE;
  float acc[8][6];
  #pragma unroll
  for (int v = 0; v < 8; ++v)
    #pragma unroll
    for (int j = 0; j < 6; ++j) acc[v][j] = 0.f;
  for (int k = 0; k < NE; ++k) {
    const float* wrow = Wt_ih + (size_t)(k + koff) * G3H;
    float w[6];
    #pragma unroll
    for (int j = 0; j < 6; ++j) w[j] = wrow[tid + j * 256];
    #pragma unroll
    for (int v = 0; v < 8; ++v) {
      float av = a[v][k];
      #pragma unroll
      for (int j = 0; j < 6; ++j) acc[v][j] += av * w[j];
    }
  }
  float* outp = is0 ? (proj0 + (size_t)g0 * G3H) : (proj1 + (size_t)(g0 - NV0) * G3H);
  for (int v = 0; v < 8; ++v)
    for (int j = 0; j < 6; ++j)
      outp[(size_t)v * G3H + tid + j * 256] = acc[v][j];
}

// W_hh split: tile tt = (hh>>4)*3 + g  (32 hh16-blocks x 3 gates = 96 tiles of 16x512)
__global__ void k_wsplit(const float* __restrict__ W_hh, u16* __restrict__ Wfh,
                         u16* __restrict__ Wfl) {
  int idx = blockIdx.x * blockDim.x + threadIdx.x;
  if (idx >= G3H * NH) return;
  int row = idx >> 9, k = idx & 511;
  int g = row >> 9, hh = row & 511;
  int tt = (hh >> 4) * 3 + g;
  size_t phys = ((size_t)tt * 64 + (k >> 3)) * 128 + (hh & 15) * 8 + (k & 7);
  float v = W_hh[idx];
  u16 hi = bf16_hi(v);
  Wfh[phys] = hi;
  Wfl[phys] = bf16_hi(v - bf16_f(hi));
}

__global__ void k_wsplit_dec(const float* __restrict__ W, u16* __restrict__ Wh,
                             u16* __restrict__ Wl, int R) {
  int idx = blockIdx.x * blockDim.x + threadIdx.x;
  if (idx >= R * 512) return;
  int row = idx >> 9, k = idx & 511;
  size_t phys = ((size_t)(row >> 4) * 64 + (k >> 3)) * 128 + (row & 15) * 8 + (k & 7);
  float v = W[idx];
  u16 hi = bf16_hi(v);
  Wh[phys] = hi;
  Wl[phys] = bf16_hi(v - bf16_f(hi));
}

// Fused planning: one block per batch. Computes levels, builds level-ordered
// item list (groups of <=16) + node_list, inits state row 0 and gdone flags.
__global__ __launch_bounds__(256) void k_plan(const int* __restrict__ cond,
                                              const float* __restrict__ hidden,
                                              u32* __restrict__ bufp,
                                              int* __restrict__ gdone,
                                              int* __restrict__ items,
                                              int* __restrict__ nitems,
                                              int* __restrict__ node_list) {
  __shared__ int c_lds[NT];
  __shared__ int lvl[NT + 1];
  __shared__ int off[NT + 1];
  int b = blockIdx.x, tid = threadIdx.x;
  for (int h = tid; h < NH; h += 256) bufp[b * NH + h] = pack_hl(hidden[b * NH + h]);
  for (int f = tid; f < 1026; f += 256) gdone[b * 1026 + f] = (f == 0) ? FLAGTGT : 0;
  for (int i = tid; i < NT; i += 256) c_lds[i] = cond[b * NT + i];
  for (int i = tid; i <= NT; i += 256) off[i] = 0;
  __syncthreads();
  if (tid == 0) {
    lvl[0] = 0;
    for (int t = 0; t < NT; ++t) {
      int l = lvl[c_lds[t]] + 1;
      lvl[t + 1] = l;
      off[l - 1]++;                       // counts
    }
    int off0 = 0, io = 0;
    for (int p = 0; p <= NT; ++p) {
      int n = off[p];
      off[p] = off0;                      // counts -> offsets
      for (int g0 = 0; g0 < n; g0 += 16) {
        int nb = n - g0; if (nb > 16) nb = 16;
        items[b * 1024 + io++] = (p << 21) | ((b * 1024 + off0 + g0) << 6) | nb;
      }
      off0 += n;
    }
    nitems[b] = io;
    for (int t = 0; t < NT; ++t) {        // scatter (offsets become cursors)
      int p = lvl[t + 1] - 1;
      node_list[b * 1024 + off[p]++] = (b << 16) | t;
    }
  }
}

// ---------------- recurrence: per-batch level streams (r10 structure) ----------------
// Grid = 16 chunks x 32 batches = 512 blocks of 128 threads (2 waves), 2 blocks/CU.
// Block (c,b) walks batch b's levels in order; a node at level p has its single
// parent at EXACTLY level p-1 (same batch), so each hop needs ONE flag:
// gdone[b][p] counted to 16 by single per-block RELEASE publishes after a
// block-wide vmcnt(0) drain + barrier (r10-proven minimum-RMW protocol; r12's
// per-wave publish doubled flag RMWs and cost ~670us).
// Poll is ALL-THREAD on the uniform flag address (saves the post-poll barrier:
// each thread's stage loads issue only after its own poll load completes).

__global__ __launch_bounds__(128, 8) void rnn_steps(
    const int* __restrict__ items, const int* __restrict__ nitems,
    const int* __restrict__ node_list, const int* __restrict__ cond,
    const int* __restrict__ tok0, const int* __restrict__ tok1,
    const u16* __restrict__ Wfh, const u16* __restrict__ Wfl,
    const float* __restrict__ proj0, const float* __restrict__ proj1,
    const float* __restrict__ b_ih, const float* __restrict__ b_hh,
    u32* __restrict__ bufp, int* gdone) {
  __shared__ unsigned char hds_h[16 * 1024];
  __shared__ unsigned char hds_l[16 * 1024];
  __shared__ int s_tb[16], s_par[16], s_k0[16], s_k1[16];
  int tid = threadIdx.x;
  int w = tid >> 6, lane = tid & 63, q = lane >> 4, m = lane & 15;
  int c = blockIdx.x & (NCHUNK - 1);
  int b = blockIdx.x >> 4;
  int nIt = nitems[b];
  const int* myItems = items + b * 1024;
  int* myGd = gdone + b * 1026;
  int prevp = -1;
  for (int j = 0; j < nIt; ++j) {
    __syncthreads();   // protect LDS from previous item
    int desc = myItems[j];
    int p = desc >> 21;
    int start = (desc >> 6) & 0x7FFF;
    int nb = desc & 63;
    if (tid < 16) {
      int bb = 0, t = -1, par = 0, q0 = 0, q1 = 0;
      if (tid < nb) {
        int pk = node_list[start + tid];
        bb = pk >> 16; t = pk & 0xFFFF;
        par = cond[bb * NT + t];
        q0 = tok0[bb * NT + t];
        q1 = tok1[bb * NT + t];
      }
      s_tb[tid] = (t + 1) * NB + bb;
      s_par[tid] = par * NB + bb;
      s_k0[tid] = q0; s_k1[tid] = q1;
    }
    __syncthreads();
    // ---- gi gather (independent of parents): seeds accumulators, pre-poll ----
    int hb = c * 2 + w;          // hh16-block owned by this wave
    int hh = hb * 16 + m;
    float bir = b_ih[hh] + b_hh[hh];
    float biz = b_ih[NH + hh] + b_hh[NH + hh];
    float bin = b_ih[2 * NH + hh];
    float bhn = b_hh[2 * NH + hh];
    f32x4 aR, aZ, aN;
    float gin[4];
    #pragma unroll
    for (int i = 0; i < 4; ++i) {
      int node = q * 4 + i;
      const float* p0 = proj0 + (size_t)s_k0[node] * G3H;
      const float* p1 = proj1 + (size_t)s_k1[node] * G3H;
      aR[i] = p0[hh] + p1[hh] + bir;
      aZ[i] = p0[NH + hh] + p1[NH + hh] + biz;
      gin[i] = p0[2 * NH + hh] + p1[2 * NH + hh] + bin;
      aN[i] = bhn;
    }
    // ---- dependency poll: ONE uniform flag, ALL threads spin (no barrier) ----
    if (p != prevp) {
      while (__hip_atomic_load(&myGd[p], __ATOMIC_RELAXED, __HIP_MEMORY_SCOPE_AGENT)
             < FLAGTGT)
        __builtin_amdgcn_s_sleep(1);
      prevp = p;
    }
    asm volatile("" ::: "memory");
    // ---- stage nb parent states into split hi/lo LDS (swizzled) ----
    for (int idx = tid; idx < nb * 16; idx += 128) {
      int r = idx >> 4, seg = idx & 15;
      size_t src = (size_t)s_par[r] * NH + seg * 32;
      u64 dv[16];
      #pragma unroll
      for (int k2 = 0; k2 < 16; ++k2)
        dv[k2] = __hip_atomic_load((const u64*)&bufp[src + k2 * 2],
                                   __ATOMIC_RELAXED, __HIP_MEMORY_SCOPE_AGENT);
      int swz = (r & 7) << 4;
      #pragma unroll
      for (int k2 = 0; k2 < 16; ++k2) {
        u32 e0 = (u32)dv[k2], e1 = (u32)(dv[k2] >> 32);
        int wi = seg * 32 + k2 * 2;
        int a = r * 1024 + (((wi >> 3) * 16) ^ swz) + ((2 * wi) & 15);
        *(u32*)(hds_h + a) = (e0 & 0xFFFFu) | (e1 << 16);
        *(u32*)(hds_l + a) = (e0 >> 16) | (e1 & 0xFFFF0000u);
      }
    }
    __syncthreads();
    // ---- MFMA: wave owns hb = c*2+w, 3 gates, 16 nodes, K=512, 3-split ----
    {
      const u16* wh = Wfh + (size_t)hb * 3 * 8192;
      const u16* wl = Wfl + (size_t)hb * 3 * 8192;
      #pragma unroll 4
      for (int s = 0; s < 16; ++s) {
        int ab = m * 1024 + (((s * 64) + (q * 16)) ^ ((m & 7) << 4));
        bf16x8 ah = *(const bf16x8*)(hds_h + ab);
        bf16x8 al = *(const bf16x8*)(hds_l + ab);
        int koff = (s * 4 + q) * 128 + m * 8;
        bf16x8 bh0 = *(const bf16x8*)(wh + koff);
        bf16x8 bl0 = *(const bf16x8*)(wl + koff);
        bf16x8 bh1 = *(const bf16x8*)(wh + 8192 + koff);
        bf16x8 bl1 = *(const bf16x8*)(wl + 8192 + koff);
        bf16x8 bh2 = *(const bf16x8*)(wh + 16384 + koff);
        bf16x8 bl2 = *(const bf16x8*)(wl + 16384 + koff);
        aR = __builtin_amdgcn_mfma_f32_16x16x32_bf16(ah, bh0, aR, 0, 0, 0);
        aR = __builtin_amdgcn_mfma_f32_16x16x32_bf16(ah, bl0, aR, 0, 0, 0);
        aR = __builtin_amdgcn_mfma_f32_16x16x32_bf16(al, bh0, aR, 0, 0, 0);
        aZ = __builtin_amdgcn_mfma_f32_16x16x32_bf16(ah, bh1, aZ, 0, 0, 0);
        aZ = __builtin_amdgcn_mfma_f32_16x16x32_bf16(ah, bl1, aZ, 0, 0, 0);
        aZ = __builtin_amdgcn_mfma_f32_16x16x32_bf16(al, bh1, aZ, 0, 0, 0);
        aN = __builtin_amdgcn_mfma_f32_16x16x32_bf16(ah, bh2, aN, 0, 0, 0);
        aN = __builtin_amdgcn_mfma_f32_16x16x32_bf16(ah, bl2, aN, 0, 0, 0);
        aN = __builtin_amdgcn_mfma_f32_16x16x32_bf16(al, bh2, aN, 0, 0, 0);
      }
      // ---- in-register GRU epilogue; packed u32 agent-atomic state stores ----
      #pragma unroll
      for (int i = 0; i < 4; ++i) {
        int node = q * 4 + i;
        if (node < nb) {
          float rg = 1.f / (1.f + __expf(-aR[i]));
          float zg = 1.f / (1.f + __expf(-aZ[i]));
          float nn = 1.f - 2.f / (1.f + __expf(2.f * (gin[i] + rg * aN[i])));
          int hofs = node * 1024 + ((hh * 2) ^ ((node & 7) << 4));
          float hp = bf16_f(*(const u16*)(hds_h + hofs)) + bf16_f(*(const u16*)(hds_l + hofs));
          float hn = (1.f - zg) * nn + zg * hp;
          __hip_atomic_store(&bufp[(size_t)s_tb[node] * NH + hh], pack_hl(hn),
                             __ATOMIC_RELAXED, __HIP_MEMORY_SCOPE_AGENT);
        }
      }
    }
    // ---- r10 publish: drain ALL threads' stores, barrier, ONE release RMW ----
    bool lastOfLevel = (j == nIt - 1) || ((myItems[j + 1] >> 21) != p);
    asm volatile("s_waitcnt vmcnt(0)" ::: "memory");
    __syncthreads();
    if (lastOfLevel && tid == 0)
      __hip_atomic_fetch_add(&myGd[p + 1], 1, __ATOMIC_RELEASE,
                             __HIP_MEMORY_SCOPE_AGENT);
  }
}

// ---------------- decode GEMM: MFMA bf16 3-split, 64x128 tiles ----------------

__global__ __launch_bounds__(256) void k_dec(const u32* __restrict__ bufp,
                                             const u16* __restrict__ Wh,
                                             const u16* __restrict__ Wl,
                                             const float* __restrict__ bias,
                                             float* __restrict__ out, int N) {
  __shared__ u16 Ah[64 * 128];
  __shared__ u16 Al[64 * 128];
  int tid = threadIdx.x;
  int w = tid >> 6, lane = tid & 63, q = lane >> 4, m = lane & 15;
  int n0 = blockIdx.x * 128, m0 = blockIdx.y * 64;
  f32x4 acc[8];
  #pragma unroll
  for (int n = 0; n < 8; ++n) acc[n] = (f32x4){0.f, 0.f, 0.f, 0.f};
  for (int c = 0; c < 4; ++c) {
    __syncthreads();
    #pragma unroll
    for (int r = 0; r < 8; ++r) {
      int idx = r * 256 + tid;           // 2048 16B-loads = 64 rows x 32 segs
      int row = idx >> 5, seg = idx & 31;
      int gm = m0 + row;
      size_t bufrow = (size_t)((gm & (NT - 1)) + 1) * NB + (gm >> 10);
      uint4 vv = *(const uint4*)(bufp + bufrow * NH + c * 128 + seg * 4);
      int a = row * 256 + (((seg >> 1) * 16) ^ ((row & 7) << 4)) + (seg & 1) * 8;
      uint2 hp, lp;
      hp.x = (vv.x & 0xFFFFu) | (vv.y << 16);
      hp.y = (vv.z & 0xFFFFu) | (vv.w << 16);
      lp.x = (vv.x >> 16) | (vv.y & 0xFFFF0000u);
      lp.y = (vv.z >> 16) | (vv.w & 0xFFFF0000u);
      *(uint2*)((unsigned char*)Ah + a) = hp;
      *(uint2*)((unsigned char*)Al + a) = lp;
    }
    __syncthreads();
    #pragma unroll
    for (int s = 0; s < 4; ++s) {
      int arow = w * 16 + m;
      int aoff = arow * 256 + (((s * 64) + (q * 16)) ^ ((arow & 7) << 4));
      bf16x8 ah = *(const bf16x8*)((unsigned char*)Ah + aoff);
      bf16x8 al = *(const bf16x8*)((unsigned char*)Al + aoff);
      #pragma unroll
      for (int n = 0; n < 8; ++n) {
        size_t bo = ((size_t)(n0 / 16 + n) * 64 + (c * 16 + s * 4 + q)) * 128 + m * 8;
        bf16x8 bh = *(const bf16x8*)(Wh + bo);
        bf16x8 bl = *(const bf16x8*)(Wl + bo);
        acc[n] = __builtin_amdgcn_mfma_f32_16x16x32_bf16(ah, bh, acc[n], 0, 0, 0);
        acc[n] = __builtin_amdgcn_mfma_f32_16x16x32_bf16(ah, bl, acc[n], 0, 0, 0);
        acc[n] = __builtin_amdgcn_mfma_f32_16x16x32_bf16(al, bh, acc[n], 0, 0, 0);
      }
    }
  }
  #pragma unroll
  for (int n = 0; n < 8; ++n) {
    int col = n0 + n * 16 + m;
    float bv = bias[col];
    #pragma unroll
    for (int i = 0; i < 4; ++i) {
      int mrow = m0 + w * 16 + q * 4 + i;
      out[(size_t)mrow * N + col] = acc[n][i] + bv;
    }
  }
}

__global__ void k_tail(const u32* __restrict__ bufp, float* __restrict__ out) {
  int i = blockIdx.x * blockDim.x + threadIdx.x;
  if (i < NB * NH) out[i] = unpack_hl(bufp[(size_t)NT * NB * NH + i]);
}

// ---------------- launch ----------------

extern "C" void kernel_launch(void* const* d_in, const int* in_sizes, int n_in,
                              void* d_out, int out_size, void* d_ws, size_t ws_size,
                              hipStream_t stream) {
  const int*   tokens0    = (const int*)d_in[0];
  const int*   tokens1    = (const int*)d_in[1];
  const int*   conditions = (const int*)d_in[2];
  const float* hidden     = (const float*)d_in[3];
  const float* emb0       = (const float*)d_in[4];
  const float* emb1       = (const float*)d_in[5];
  const float* W_ih       = (const float*)d_in[6];
  const float* W_hh       = (const float*)d_in[7];
  const float* b_ih       = (const float*)d_in[8];
  const float* b_hh       = (const float*)d_in[9];
  const float* dec0_W     = (const float*)d_in[10];
  const float* dec0_b     = (const float*)d_in[11];
  const float* dec1_W     = (const float*)d_in[12];
  const float* dec1_b     = (const float*)d_in[13];

  char* wsb = (char*)d_ws;
  float* proj0 = (float*)wsb;                      // 12,582,912 B
  float* proj1 = (float*)(wsb + 12582912);         //  3,145,728 B
  float* Wt_ih = (float*)(wsb + 15728640);         //  3,145,728 B (reused below)
  // gdone/items/nitems overlay Wt_ih's region: used only AFTER k_proj
  int*   gdone   = (int*)(wsb + 15728640);         // 32*1026 ints = 131,328 B
  int*   items   = (int*)(wsb + 15859968);         // 32*1024 ints = 131,072 B
  int*   nitems  = (int*)(wsb + 15991040);         // 32 ints
  u32*   bufp  = (u32*)(wsb + 18874368);           // 1025*32*512 u32 = 67,174,400 B
  u16*   Wfh   = (u16*)(wsb + 86048768);           //  1,572,864 B
  u16*   Wfl   = (u16*)(wsb + 87621632);           //  1,572,864 B
  u16*   d0Wh  = (u16*)(wsb + 89194496);           //  2,097,152 B
  u16*   d0Wl  = (u16*)(wsb + 91291648);           //  2,097,152 B
  u16*   d1Wh  = (u16*)(wsb + 93388800);           //    524,288 B
  u16*   d1Wl  = (u16*)(wsb + 93913088);           //    524,288 B
  int*   node_list = (int*)(wsb + 94437376);       // 32768 ints

  float* out0 = (float*)d_out;
  float* out1 = out0 + (size_t)NB * NT * NV0;
  float* outT = out1 + (size_t)NB * NT * NV1;

  // Wt_ih produced+consumed first; then its region is reused for dataflow state.
  k_transpose<<<dim3(16, 48), dim3(32, 8), 0, stream>>>(W_ih, Wt_ih);
  k_proj<<<320, 256, 0, stream>>>(emb0, emb1, Wt_ih, proj0, proj1);
  k_wsplit<<<3072, 256, 0, stream>>>(W_hh, Wfh, Wfl);
  k_wsplit_dec<<<4096, 256, 0, stream>>>(dec0_W, d0Wh, d0Wl, NV0);
  k_wsplit_dec<<<1024, 256, 0, stream>>>(dec1_W, d1Wh, d1Wl, NV1);
  k_plan<<<NB, 256, 0, stream>>>(conditions, hidden, bufp, gdone, items, nitems,
                                 node_list);

  rnn_steps<<<NCHUNK * NB, 128, 0, stream>>>(items, nitems, node_list, conditions,
                                             tokens0, tokens1, Wfh, Wfl, proj0, proj1,
                                             b_ih, b_hh, bufp, gdone);

  k_dec<<<dim3(NV0 / 128, (NB * NT) / 64), 256, 0, stream>>>(bufp, d0Wh, d0Wl, dec0_b, out0, NV0);
  k_dec<<<dim3(NV1 / 128, (NB * NT) / 64), 256, 0, stream>>>(bufp, d1Wh, d1Wl, dec1_b, out1, NV1);
  k_tail<<<64, 256, 0, stream>>>(bufp, outT);
}